// Round 15
// baseline (232.364 us; speedup 1.0000x reference)
//
#include <hip/hip_runtime.h>
#include <math.h>

#define DIMN 1024
#define NH 8
#define ND 64
#define LSEQ 256
#define HD 512      // NH*ND

typedef __attribute__((ext_vector_type(8))) short short8;
typedef __attribute__((ext_vector_type(4))) float f32x4;

__device__ __forceinline__ float2 cmul(float2 a, float2 b){
    return make_float2(a.x*b.x - a.y*b.y, a.x*b.y + a.y*b.x);
}
__device__ __forceinline__ ushort f2bf(float f){
    union { float f; unsigned u; } v; v.f = f;
    unsigned r = v.u + 0x7FFF + ((v.u >> 16) & 1);   // RNE
    return (ushort)(r >> 16);
}

#define ISTR 65

// ---------- blocked (NB=16) in-place Gauss-Jordan, 512 threads ----------
// R11 structure widened 8->16: 4 macro-steps, 12 barriers (was 24). Wave 0
// factorizes the 64x16 panel in registers (static indices only); all waves
// apply the rank-16 update. Algebra identical to the R11-verified version.
__device__ __forceinline__ void inv_gj_blocked(const float* __restrict__ Vr,
        const float* __restrict__ Vi, float2* __restrict__ Vinv,
        int h, int tid, float2* Mx){
    for (int idx = tid; idx < 4096; idx += 512){
        int i = idx >> 6, j = idx & 63;
        Mx[i*ISTR + j] = make_float2(Vr[h*4096 + idx], Vi[h*4096 + idx]);
    }
    __syncthreads();
    const int w = tid >> 6, l = tid & 63;
    const int rbase = w*8;
    for (int kb = 0; kb < 4; ++kb){
        const int k0 = kb*16;
        if (w == 0){
            // ---- panel factorization: lane l = row l, pr[m] = panel cols ----
            float2 pr[16];
            #pragma unroll
            for (int m = 0; m < 16; ++m) pr[m] = Mx[l*ISTR + k0 + m];
            #pragma unroll
            for (int k = 0; k < 16; ++k){
                const int gk = k0 + k;
                float2 d; d.x = __shfl(pr[k].x, gk); d.y = __shfl(pr[k].y, gk);
                float im = 1.f/(d.x*d.x + d.y*d.y);
                float2 p = make_float2(d.x*im, -d.y*im);
                float2 spr[16];
                #pragma unroll
                for (int m = 0; m < 16; ++m){
                    float2 t; t.x = __shfl(pr[m].x, gk); t.y = __shfl(pr[m].y, gk);
                    spr[m] = (m == k) ? p : cmul(t, p);
                }
                float2 f = pr[k];
                if (l == gk){
                    #pragma unroll
                    for (int m = 0; m < 16; ++m) pr[m] = spr[m];
                } else {
                    #pragma unroll
                    for (int m = 0; m < 16; ++m){
                        float2 u = cmul(f, spr[m]);
                        if (m == k){ pr[m].x = -u.x;  pr[m].y = -u.y;  }
                        else       { pr[m].x -= u.x;  pr[m].y -= u.y;  }
                    }
                }
            }
            #pragma unroll
            for (int m = 0; m < 16; ++m) Mx[l*ISTR + k0 + m] = pr[m];
        }
        __syncthreads();            // B1: panel visible
        float2 br[16];              // block rows, my column
        #pragma unroll
        for (int m = 0; m < 16; ++m) br[m] = Mx[(k0+m)*ISTR + l];
        __syncthreads();            // B2: cross-reads done before writes
        if (((unsigned)(l - k0)) >= 16u){    // block columns are final; skip
            #pragma unroll
            for (int rr = 0; rr < 8; ++rr){
                const int r = rbase + rr;
                float2 acc;
                if (((unsigned)(r - k0)) < 16u){ acc.x = 0.f; acc.y = 0.f; }
                else acc = Mx[r*ISTR + l];
                #pragma unroll
                for (int m = 0; m < 16; ++m){
                    float2 Pv = Mx[r*ISTR + k0 + m];   // wave-uniform broadcast
                    acc.x += Pv.x*br[m].x - Pv.y*br[m].y;
                    acc.y += Pv.x*br[m].y + Pv.y*br[m].x;
                }
                Mx[r*ISTR + l] = acc;
            }
        }
        __syncthreads();            // B3: writes done before next panel
    }
    for (int idx = tid; idx < 4096; idx += 512){
        int i = idx >> 6, j = idx & 63;
        Vinv[h*4096 + idx] = Mx[i*ISTR + j];
    }
}

// ---------- fused prep: blocks 0-7 = per-head inverse (blocked GJ);
// blocks 8-135 = x->bf16 cast; blocks 136+ = weight transposes (2 tiles/blk).
__global__ __launch_bounds__(512) void prep_kernel(
        const float* __restrict__ x,
        const float* __restrict__ w1, const float* __restrict__ w2,
        const float* __restrict__ w3, const float* __restrict__ w4,
        const float* __restrict__ Vr, const float* __restrict__ Vi,
        ushort* __restrict__ x_bf,
        ushort* __restrict__ w1t, ushort* __restrict__ w2t,
        ushort* __restrict__ w3t, ushort* __restrict__ w4t,
        float2* __restrict__ Vinv){
    __shared__ float2 Mx[64*ISTR];
    const int b = blockIdx.x;
    const int tid = threadIdx.x;

    if (b < 8){
        inv_gj_blocked(Vr, Vi, Vinv, b, tid, Mx);
        return;
    }

    int widx = b - 8;
    if (widx < 128){
        int i = widx*512 + tid;
        float4 v = ((const float4*)x)[i];
        ushort4 u; u.x=f2bf(v.x); u.y=f2bf(v.y); u.z=f2bf(v.z); u.w=f2bf(v.w);
        ((ushort4*)x_bf)[i] = u;
        return;
    }
    widx -= 128;

    const float* W; ushort* Wt; int K = 1024, N;
    if (widx < 512)            { W = w1; Wt = w1t; N = 1024; }
    else if (widx < 1536)      { W = w2; Wt = w2t; N = 2048; widx -= 512; }
    else if (widx < 2048)      { W = w3; Wt = w3t; N = 1024; widx -= 1536; }
    else                       { W = w4; Wt = w4t; N = 1024; widx -= 2048; }
    const int half = tid >> 8;
    const int t = widx*2 + half;
    const int tiles_n = N >> 5;
    const int n0 = (t % tiles_n) * 32, k0 = (t / tiles_n) * 32;
    float* tile = (float*)Mx + half*(32*33);
    const int tx = tid & 31, ty = (tid >> 5) & 7;
    #pragma unroll
    for (int i = 0; i < 4; ++i)
        tile[(ty + i*8)*33 + tx] = W[(k0 + ty + i*8)*N + n0 + tx];
    __syncthreads();
    #pragma unroll
    for (int i = 0; i < 4; ++i){
        int r = ty + i*8;
        Wt[(n0 + r)*K + k0 + tx] = f2bf(tile[tx*33 + r]);
    }
}

// ---------- serial-fallback kernels (used only if ws too small) ----------
__global__ __launch_bounds__(512) void inv_kernel(const float* __restrict__ Vr,
                                                  const float* __restrict__ Vi,
                                                  float2* __restrict__ Vinv){
    __shared__ float2 Mx[64*ISTR];
    inv_gj_blocked(Vr, Vi, Vinv, blockIdx.x, threadIdx.x, Mx);
}

__global__ __launch_bounds__(256) void transpose_cvt(const float* __restrict__ W,
                 ushort* __restrict__ Wt, int K, int N){
    __shared__ float tile[32][33];
    const int n0 = blockIdx.x * 32, k0 = blockIdx.y * 32;
    const int tx = threadIdx.x & 31, ty = threadIdx.x >> 5;
    #pragma unroll
    for (int i = 0; i < 4; ++i)
        tile[ty + i*8][tx] = W[(k0 + ty + i*8)*N + n0 + tx];
    __syncthreads();
    #pragma unroll
    for (int i = 0; i < 4; ++i){
        int r = ty + i*8;
        Wt[(n0 + r)*K + k0 + tx] = f2bf(tile[tx][r]);
    }
}

__global__ __launch_bounds__(256) void cvt_bf16_kernel(const float* __restrict__ in,
                                 ushort* __restrict__ o, int n4){
    int i = blockIdx.x*256 + threadIdx.x;
    if (i < n4){
        float4 v = ((const float4*)in)[i];
        ushort4 u; u.x=f2bf(v.x); u.y=f2bf(v.y); u.z=f2bf(v.z); u.w=f2bf(v.w);
        ((ushort4*)o)[i] = u;
    }
}

// ---------- bf16 MFMA GEMM, 64x64 tile (R14-verified) ----------
#define BM 64
#define BN 64
#define BK 32
#define ASTR 40
template<int ACT>
__global__ __launch_bounds__(256) void gemm_bt(const ushort* __restrict__ A,
                 const ushort* __restrict__ Bt, const float* __restrict__ bias,
                 float* __restrict__ Cf, ushort* __restrict__ Cb,
                 float2* __restrict__ XCo, float2* __restrict__ Ao,
                 int M, int N, int K){
    __shared__ ushort As[BM*ASTR];
    __shared__ ushort Bs[BN*ASTR];
    const int tid = threadIdx.x;
    const int bm = blockIdx.y * BM, bn = blockIdx.x * BN;
    const int wave = tid >> 6, l = tid & 63;
    const int wr = (wave >> 1) * 32, wc = (wave & 1) * 32;
    const int ml = l & 15, quad = l >> 4;
    f32x4 acc[2][2];
    #pragma unroll
    for (int i=0;i<2;++i)
        #pragma unroll
        for (int j=0;j<2;++j) acc[i][j] = (f32x4){0.f,0.f,0.f,0.f};
    const int c0r = tid >> 2;
    const int c0s = tid & 3;
    for (int k0 = 0; k0 < K; k0 += BK){
        uint4 av = *(const uint4*)&A [(bm + c0r)*K + k0 + c0s*8];
        uint4 bv = *(const uint4*)&Bt[(bn + c0r)*K + k0 + c0s*8];
        __syncthreads();
        *(uint4*)&As[c0r*ASTR + c0s*8] = av;
        *(uint4*)&Bs[c0r*ASTR + c0s*8] = bv;
        __syncthreads();
        short8 af[2], bfv[2];
        #pragma unroll
        for (int f=0; f<2; ++f){
            af[f]  = *(const short8*)&As[(wr + f*16 + ml)*ASTR + quad*8];
            bfv[f] = *(const short8*)&Bs[(wc + f*16 + ml)*ASTR + quad*8];
        }
        #pragma unroll
        for (int i=0;i<2;++i)
            #pragma unroll
            for (int j=0;j<2;++j)
                acc[i][j] = __builtin_amdgcn_mfma_f32_16x16x32_bf16(af[i], bfv[j], acc[i][j], 0,0,0);
    }
    #pragma unroll
    for (int i=0;i<2;++i){
        #pragma unroll
        for (int j=0;j<2;++j){
            const int gcol = bn + wc + j*16 + ml;
            const float bsv = bias[gcol];
            #pragma unroll
            for (int r=0;r<4;++r){
                const int grow = bm + wr + i*16 + quad*4 + r;
                float val = acc[i][j][r] + bsv;
                if (ACT == 2){
                    float v1 = __shfl_down(val, 1);
                    float v2 = __shfl_down(val, 2);
                    float v3 = __shfl_down(val, 3);
                    if ((l & 3) == 0){
                        int hd = gcol >> 2;
                        XCo[grow*HD + hd] = make_float2(val, v1);
                        float m2 = v2*v2 + v3*v3;
                        float s = sqrtf(m2)/(1.f + m2);
                        Ao[grow*HD + hd] = make_float2(v2*s, v3*s);
                    }
                } else if (ACT == 1){
                    val *= 1.f/(1.f + expf(-val));
                    Cb[grow*N + gcol] = f2bf(val);
                } else {
                    Cf[grow*N + gcol] = val;
                }
            }
        }
    }
}

// ---------- fused uext + parallel scan (verified R12/R13) ----------
__global__ __launch_bounds__(512) void upscan_kernel(const float2* __restrict__ Vinv,
        const float* __restrict__ hidr, const float* __restrict__ him,
        const float2* __restrict__ XC, const float2* __restrict__ Aseq,
        float2* __restrict__ S){
    __shared__ float4 buf[2][2][LSEQ];
    __shared__ float2 vrow[2][64];
    __shared__ float2 inu[2];
    const int b = blockIdx.x;
    const int tid = threadIdx.x;
    const int g = tid >> 8, m = tid & 255;
    const int hn = b*2 + g;
    const int h = hn >> 6;
    if (m < 64) vrow[g][m] = Vinv[hn*64 + m];
    __syncthreads();
    float2 acc = make_float2(0.f, 0.f);
    const float2* xrow = &XC[m*HD + h*64];
    #pragma unroll 8
    for (int o=0;o<64;++o){
        float2 p = cmul(vrow[g][o], xrow[o]);
        acc.x += p.x; acc.y += p.y;
    }
    if (m == 0){
        float2 i0 = make_float2(0.f, 0.f);
        #pragma unroll 8
        for (int o=0;o<64;++o){
            float2 hv = make_float2(hidr[h*64+o], him[h*64+o]);
            float2 p = cmul(vrow[g][o], hv);
            i0.x += p.x; i0.y += p.y;
        }
        inu[g] = i0;
    }
    float2 a = Aseq[m*HD + hn];
    buf[0][g][m] = make_float4(a.x, a.y, acc.x, acc.y);
    __syncthreads();
    int pb = 0;
    #pragma unroll
    for (int d = 1; d < LSEQ; d <<= 1){
        float4 cur = buf[pb][g][m];
        float4 o2 = cur;
        if (m >= d){
            float4 prev = buf[pb][g][m-d];
            float2 cA = make_float2(cur.x, cur.y), cU = make_float2(cur.z, cur.w);
            float2 pA = make_float2(prev.x, prev.y), pU = make_float2(prev.z, prev.w);
            float2 nA = cmul(cA, pA);
            float2 nU = cmul(cA, pU);
            nU.x += cU.x; nU.y += cU.y;
            o2 = make_float4(nA.x, nA.y, nU.x, nU.y);
        }
        buf[pb^1][g][m] = o2;
        pb ^= 1;
        __syncthreads();
    }
    float4 t = buf[pb][g][m];
    float2 init = inu[g];
    float2 st = cmul(make_float2(t.x, t.y), init);
    st.x += t.z; st.y += t.w;
    S[m*HD + hn] = st;
}

// ---------- h[m] = V_h @ S[m]; hr as bf16; fp32 tail ----------
__global__ __launch_bounds__(256) void vmul_kernel(const float* __restrict__ Vr,
                            const float* __restrict__ Vi,
                            const float2* __restrict__ S, ushort* __restrict__ hrb,
                            float* __restrict__ out_tail, int tail_n){
    int g = blockIdx.x*256 + threadIdx.x;
    int m = g >> 9, hn = g & 511;
    int h = hn >> 6;
    const float* vr = &Vr[hn*64];
    const float* vi = &Vi[hn*64];
    const float2* srow = &S[m*HD + h*64];
    float2 acc = make_float2(0.f, 0.f);
    #pragma unroll 8
    for (int o=0;o<64;++o){
        float2 v = make_float2(vr[o], vi[o]);
        float2 p = cmul(v, srow[o]);
        acc.x += p.x; acc.y += p.y;
    }
    hrb[m*DIMN + hn*2]   = f2bf(acc.x);
    hrb[m*DIMN + hn*2+1] = f2bf(acc.y);
    if (m == LSEQ-1){
        if (tail_n >= 1024){
            out_tail[hn]       = acc.x;
            out_tail[512 + hn] = acc.y;
        } else if (tail_n >= 512){
            out_tail[hn] = acc.x;
        }
    }
}

extern "C" void kernel_launch(void* const* d_in, const int* in_sizes, int n_in,
                              void* d_out, int out_size, void* d_ws, size_t ws_size,
                              hipStream_t stream) {
    const float* x      = (const float*)d_in[0];
    const float* hidr   = (const float*)d_in[1];
    const float* hidi   = (const float*)d_in[2];
    const float* w_in1  = (const float*)d_in[3];
    const float* b_in1  = (const float*)d_in[4];
    const float* w_in2  = (const float*)d_in[5];
    const float* b_in2  = (const float*)d_in[6];
    const float* w_out1 = (const float*)d_in[7];
    const float* b_out1 = (const float*)d_in[8];
    const float* w_out2 = (const float*)d_in[9];
    const float* b_out2 = (const float*)d_in[10];
    const float* Vr     = (const float*)d_in[11];
    const float* Vi     = (const float*)d_in[12];
    float* out = (float*)d_out;
    const int tail_n = out_size - LSEQ*DIMN;
    char* ws = (char*)d_ws;

    if (ws_size >= 14946304u){
        float2* Vinv  = (float2*)(ws + 0);          // 262144
        ushort* w1t   = (ushort*)(ws + 262144);     // 2 MB
        ushort* w2t   = (ushort*)(ws + 2359296);    // 4 MB
        ushort* w3t   = (ushort*)(ws + 6553600);    // 2 MB
        ushort* w4t   = (ushort*)(ws + 8650752);    // 2 MB
        ushort* x_bf  = (ushort*)(ws + 10747904);   // 512 KB (reused as y1_bf)
        ushort* t1_bf = (ushort*)(ws + 11272192);   // 512 KB (reused as hr_bf)
        float2* XC    = (float2*)(ws + 11796480);   // 1 MB
        float2* Aseq  = (float2*)(ws + 12845056);   // 1 MB
        float2* S     = (float2*)(ws + 13893632);   // 1 MB (must not alias XC)
        ushort* y1_bf = x_bf;
        ushort* hr_bf = t1_bf;

        prep_kernel<<<2696, 512, 0, stream>>>(x, w_in1, w_in2, w_out1, w_out2,
                                              Vr, Vi, x_bf, w1t, w2t, w3t, w4t, Vinv);
        gemm_bt<1><<<dim3(16,4), 256, 0, stream>>>(x_bf, w1t, b_in1, nullptr, t1_bf,
                                                   nullptr, nullptr, LSEQ, DIMN, DIMN);
        gemm_bt<2><<<dim3(32,4), 256, 0, stream>>>(t1_bf, w2t, b_in2, nullptr, nullptr,
                                                   XC, Aseq, LSEQ, 2048, DIMN);
        upscan_kernel<<<256, 512, 0, stream>>>(Vinv, hidr, hidi, XC, Aseq, S);
        vmul_kernel<<<LSEQ*HD/256, 256, 0, stream>>>(Vr, Vi, S, hr_bf, out + LSEQ*DIMN, tail_n);
        gemm_bt<1><<<dim3(16,4), 256, 0, stream>>>(hr_bf, w3t, b_out1, nullptr, y1_bf,
                                                   nullptr, nullptr, LSEQ, DIMN, DIMN);
        gemm_bt<0><<<dim3(16,4), 256, 0, stream>>>(y1_bf, w4t, b_out2, out, nullptr,
                                                   nullptr, nullptr, LSEQ, DIMN, DIMN);
    } else {
        float2* Vinv  = (float2*)(ws + 0);
        ushort* wt    = (ushort*)(ws + 262144);
        ushort* x_bf  = (ushort*)(ws + 4456448);
        ushort* t1_bf = (ushort*)(ws + 4980736);
        float2* XC    = (float2*)(ws + 5505024);
        float2* Aseq  = (float2*)(ws + 6553600);
        float2* S     = (float2*)(ws + 7602176);    // not aliasing XC
        ushort* y1_bf = x_bf;
        ushort* hr_bf = t1_bf;

        inv_kernel<<<NH, 512, 0, stream>>>(Vr, Vi, Vinv);
        cvt_bf16_kernel<<<LSEQ*DIMN/4/256, 256, 0, stream>>>(x, x_bf, LSEQ*DIMN/4);
        transpose_cvt<<<dim3(32,32), 256, 0, stream>>>(w_in1, wt, DIMN, DIMN);
        gemm_bt<1><<<dim3(16,4), 256, 0, stream>>>(x_bf, wt, b_in1, nullptr, t1_bf,
                                                   nullptr, nullptr, LSEQ, DIMN, DIMN);
        transpose_cvt<<<dim3(64,32), 256, 0, stream>>>(w_in2, wt, DIMN, 2048);
        gemm_bt<2><<<dim3(32,4), 256, 0, stream>>>(t1_bf, wt, b_in2, nullptr, nullptr,
                                                   XC, Aseq, LSEQ, 2048, DIMN);
        upscan_kernel<<<256, 512, 0, stream>>>(Vinv, hidr, hidi, XC, Aseq, S);
        vmul_kernel<<<LSEQ*HD/256, 256, 0, stream>>>(Vr, Vi, S, hr_bf, out + LSEQ*DIMN, tail_n);
        transpose_cvt<<<dim3(32,32), 256, 0, stream>>>(w_out1, wt, DIMN, DIMN);
        gemm_bt<1><<<dim3(16,4), 256, 0, stream>>>(hr_bf, wt, b_out1, nullptr, y1_bf,
                                                   nullptr, nullptr, LSEQ, DIMN, DIMN);
        transpose_cvt<<<dim3(32,32), 256, 0, stream>>>(w_out2, wt, DIMN, DIMN);
        gemm_bt<0><<<dim3(16,4), 256, 0, stream>>>(y1_bf, wt, b_out2, out, nullptr,
                                                   nullptr, nullptr, LSEQ, DIMN, DIMN);
    }
}

// Round 16
// 212.688 us; speedup vs baseline: 1.0925x; 1.0925x over previous
//
#include <hip/hip_runtime.h>
#include <math.h>

#define DIMN 1024
#define NH 8
#define ND 64
#define LSEQ 256
#define HD 512      // NH*ND

typedef __attribute__((ext_vector_type(8))) short short8;
typedef __attribute__((ext_vector_type(4))) float f32x4;

__device__ __forceinline__ float2 cmul(float2 a, float2 b){
    return make_float2(a.x*b.x - a.y*b.y, a.x*b.y + a.y*b.x);
}
__device__ __forceinline__ ushort f2bf(float f){
    union { float f; unsigned u; } v; v.f = f;
    unsigned r = v.u + 0x7FFF + ((v.u >> 16) & 1);   // RNE
    return (ushort)(r >> 16);
}

#define ISTR 65

// ---------- blocked (NB=8) in-place Gauss-Jordan (R11/R14-verified; NB=16 regressed R15) ----------
__device__ __forceinline__ void inv_gj_blocked(const float* __restrict__ Vr,
        const float* __restrict__ Vi, float2* __restrict__ Vinv,
        int h, int tid, float2* Mx){
    for (int idx = tid; idx < 4096; idx += 512){
        int i = idx >> 6, j = idx & 63;
        Mx[i*ISTR + j] = make_float2(Vr[h*4096 + idx], Vi[h*4096 + idx]);
    }
    __syncthreads();
    const int w = tid >> 6, l = tid & 63;
    const int rbase = w*8;
    for (int kb = 0; kb < 8; ++kb){
        const int k0 = kb*8;
        if (w == 0){
            float2 pr[8];
            #pragma unroll
            for (int m = 0; m < 8; ++m) pr[m] = Mx[l*ISTR + k0 + m];
            #pragma unroll
            for (int k = 0; k < 8; ++k){
                const int gk = k0 + k;
                float2 d; d.x = __shfl(pr[k].x, gk); d.y = __shfl(pr[k].y, gk);
                float im = 1.f/(d.x*d.x + d.y*d.y);
                float2 p = make_float2(d.x*im, -d.y*im);
                float2 spr[8];
                #pragma unroll
                for (int m = 0; m < 8; ++m){
                    float2 t; t.x = __shfl(pr[m].x, gk); t.y = __shfl(pr[m].y, gk);
                    spr[m] = (m == k) ? p : cmul(t, p);
                }
                float2 f = pr[k];
                if (l == gk){
                    #pragma unroll
                    for (int m = 0; m < 8; ++m) pr[m] = spr[m];
                } else {
                    #pragma unroll
                    for (int m = 0; m < 8; ++m){
                        float2 u = cmul(f, spr[m]);
                        if (m == k){ pr[m].x = -u.x;  pr[m].y = -u.y;  }
                        else       { pr[m].x -= u.x;  pr[m].y -= u.y;  }
                    }
                }
            }
            #pragma unroll
            for (int m = 0; m < 8; ++m) Mx[l*ISTR + k0 + m] = pr[m];
        }
        __syncthreads();
        float2 br[8];
        #pragma unroll
        for (int m = 0; m < 8; ++m) br[m] = Mx[(k0+m)*ISTR + l];
        __syncthreads();
        if (((unsigned)(l - k0)) >= 8u){
            #pragma unroll
            for (int rr = 0; rr < 8; ++rr){
                const int r = rbase + rr;
                float2 acc;
                if (((unsigned)(r - k0)) < 8u){ acc.x = 0.f; acc.y = 0.f; }
                else acc = Mx[r*ISTR + l];
                #pragma unroll
                for (int m = 0; m < 8; ++m){
                    float2 Pv = Mx[r*ISTR + k0 + m];
                    acc.x += Pv.x*br[m].x - Pv.y*br[m].y;
                    acc.y += Pv.x*br[m].y + Pv.y*br[m].x;
                }
                Mx[r*ISTR + l] = acc;
            }
        }
        __syncthreads();
    }
    for (int idx = tid; idx < 4096; idx += 512){
        int i = idx >> 6, j = idx & 63;
        Vinv[h*4096 + idx] = Mx[i*ISTR + j];
    }
}

// ---------- W3eff tile: W3bt[n, c'] = bf16( sum_dd V-contraction with w3 ) ----------
// y1pre[m,n] = sum_{h,o} Sre[m,h,o]*Wre + Sim[m,h,o]*Wim  where
// Wre[(h,o),n] = sum_dd  Vr[h64+dd,o]*w3[2(h64+dd),n] + Vi[h64+dd,o]*w3[2(h64+dd)+1,n]
// Wim[(h,o),n] = sum_dd -Vi[h64+dd,o]*w3[2(h64+dd),n] + Vr[h64+dd,o]*w3[2(h64+dd)+1,n]
// (exactly vmul∘gemm3 re-associated; verified by substitution)
__device__ __forceinline__ void w3eff_tile(const float* __restrict__ Vr,
        const float* __restrict__ Vi, const float* __restrict__ w3,
        ushort* __restrict__ W3bt, int t, int tid, float* lds){
    const int n0 = (t & 31)*32;
    const int c0 = (t >> 5)*32;
    const int h  = c0 >> 7;
    const int og0 = (c0 & 127) >> 1;
    float* Vbr = lds;            // 64 x 16
    float* Vbi = lds + 1024;     // 64 x 16
    float* Wb  = lds + 2048;     // 128 x 32
    for (int q = tid; q < 1024; q += 512){
        int dd = q >> 4, oo = q & 15;
        Vbr[q] = Vr[(h*64+dd)*64 + og0 + oo];
        Vbi[q] = Vi[(h*64+dd)*64 + og0 + oo];
    }
    for (int q = tid; q < 4096; q += 512){
        int row = q >> 5, nn = q & 31;
        Wb[q] = w3[(h*128 + row)*1024 + n0 + nn];
    }
    __syncthreads();
    const int nn = tid & 31, oo = tid >> 5;    // oo 0..15
    float ar = 0.f, ai = 0.f;
    #pragma unroll 8
    for (int dd = 0; dd < 64; ++dd){
        float vr = Vbr[dd*16 + oo], vi = Vbi[dd*16 + oo];
        float w0 = Wb[(dd*2)*32 + nn], w1v = Wb[(dd*2+1)*32 + nn];
        ar += vr*w0 + vi*w1v;
        ai += -vi*w0 + vr*w1v;
    }
    W3bt[(n0+nn)*1024 + c0 + oo*2 + 0] = f2bf(ar);
    W3bt[(n0+nn)*1024 + c0 + oo*2 + 1] = f2bf(ai);
}

// ---------- fused prep: blocks 0-7 inverse; 8-135 x->bf16; then 2048 transpose
// units (w1,w2,w4; w3 dropped) + 1024 W3eff units. Grid 3208.
__global__ __launch_bounds__(512) void prep_kernel(
        const float* __restrict__ x,
        const float* __restrict__ w1, const float* __restrict__ w2,
        const float* __restrict__ w3, const float* __restrict__ w4,
        const float* __restrict__ Vr, const float* __restrict__ Vi,
        ushort* __restrict__ x_bf,
        ushort* __restrict__ w1t, ushort* __restrict__ w2t,
        ushort* __restrict__ W3bt, ushort* __restrict__ w4t,
        float2* __restrict__ Vinv){
    __shared__ float2 Mx[64*ISTR];
    const int b = blockIdx.x;
    const int tid = threadIdx.x;

    if (b < 8){
        inv_gj_blocked(Vr, Vi, Vinv, b, tid, Mx);
        return;
    }

    int widx = b - 8;
    if (widx < 128){
        int i = widx*512 + tid;
        float4 v = ((const float4*)x)[i];
        ushort4 u; u.x=f2bf(v.x); u.y=f2bf(v.y); u.z=f2bf(v.z); u.w=f2bf(v.w);
        ((ushort4*)x_bf)[i] = u;
        return;
    }
    widx -= 128;

    if (widx >= 2048){
        w3eff_tile(Vr, Vi, w3, W3bt, widx - 2048, tid, (float*)Mx);
        return;
    }

    const float* W; ushort* Wt; int K = 1024, N;
    if (widx < 512)            { W = w1; Wt = w1t; N = 1024; }
    else if (widx < 1536)      { W = w2; Wt = w2t; N = 2048; widx -= 512; }
    else                       { W = w4; Wt = w4t; N = 1024; widx -= 1536; }
    const int half = tid >> 8;
    const int t = widx*2 + half;
    const int tiles_n = N >> 5;
    const int n0 = (t % tiles_n) * 32, k0 = (t / tiles_n) * 32;
    float* tile = (float*)Mx + half*(32*33);
    const int tx = tid & 31, ty = (tid >> 5) & 7;
    #pragma unroll
    for (int i = 0; i < 4; ++i)
        tile[(ty + i*8)*33 + tx] = W[(k0 + ty + i*8)*N + n0 + tx];
    __syncthreads();
    #pragma unroll
    for (int i = 0; i < 4; ++i){
        int r = ty + i*8;
        Wt[(n0 + r)*K + k0 + tx] = f2bf(tile[tx*33 + r]);
    }
}

// ---------- serial-fallback kernels (R14 path; used only if ws too small) ----------
__global__ __launch_bounds__(512) void inv_kernel(const float* __restrict__ Vr,
                                                  const float* __restrict__ Vi,
                                                  float2* __restrict__ Vinv){
    __shared__ float2 Mx[64*ISTR];
    inv_gj_blocked(Vr, Vi, Vinv, blockIdx.x, threadIdx.x, Mx);
}

__global__ __launch_bounds__(256) void transpose_cvt(const float* __restrict__ W,
                 ushort* __restrict__ Wt, int K, int N){
    __shared__ float tile[32][33];
    const int n0 = blockIdx.x * 32, k0 = blockIdx.y * 32;
    const int tx = threadIdx.x & 31, ty = threadIdx.x >> 5;
    #pragma unroll
    for (int i = 0; i < 4; ++i)
        tile[ty + i*8][tx] = W[(k0 + ty + i*8)*N + n0 + tx];
    __syncthreads();
    #pragma unroll
    for (int i = 0; i < 4; ++i){
        int r = ty + i*8;
        Wt[(n0 + r)*K + k0 + tx] = f2bf(tile[tx][r]);
    }
}

__global__ __launch_bounds__(256) void cvt_bf16_kernel(const float* __restrict__ in,
                                 ushort* __restrict__ o, int n4){
    int i = blockIdx.x*256 + threadIdx.x;
    if (i < n4){
        float4 v = ((const float4*)in)[i];
        ushort4 u; u.x=f2bf(v.x); u.y=f2bf(v.y); u.z=f2bf(v.z); u.w=f2bf(v.w);
        ((ushort4*)o)[i] = u;
    }
}

// ---------- bf16 MFMA GEMM, 64x64 tile (R14-verified). ACT0 block(0,0) also
// computes the fp32 hidden_next tail from S255 (fused former vmul-tail). ----------
#define BM 64
#define BN 64
#define BK 32
#define ASTR 40
template<int ACT>
__global__ __launch_bounds__(256) void gemm_bt(const ushort* __restrict__ A,
                 const ushort* __restrict__ Bt, const float* __restrict__ bias,
                 float* __restrict__ Cf, ushort* __restrict__ Cb,
                 float2* __restrict__ XCo, float2* __restrict__ Ao,
                 int M, int N, int K,
                 const float* __restrict__ tVr, const float* __restrict__ tVi,
                 const float2* __restrict__ S255, float* __restrict__ out_tail,
                 int tail_n){
    __shared__ ushort As[BM*ASTR];
    __shared__ ushort Bs[BN*ASTR];
    const int tid = threadIdx.x;
    const int bm = blockIdx.y * BM, bn = blockIdx.x * BN;
    const int wave = tid >> 6, l = tid & 63;
    const int wr = (wave >> 1) * 32, wc = (wave & 1) * 32;
    const int ml = l & 15, quad = l >> 4;

    if (ACT == 0 && out_tail != nullptr && blockIdx.x == 0 && blockIdx.y == 0){
        for (int hn = tid; hn < 512; hn += 256){
            int h = hn >> 6;
            float2 acc2 = make_float2(0.f, 0.f);
            #pragma unroll 8
            for (int o = 0; o < 64; ++o){
                float2 v = make_float2(tVr[hn*64+o], tVi[hn*64+o]);
                float2 p = cmul(v, S255[h*64+o]);
                acc2.x += p.x; acc2.y += p.y;
            }
            if (tail_n >= 1024){
                out_tail[hn]       = acc2.x;
                out_tail[512 + hn] = acc2.y;
            } else if (tail_n >= 512){
                out_tail[hn] = acc2.x;
            }
        }
    }

    f32x4 acc[2][2];
    #pragma unroll
    for (int i=0;i<2;++i)
        #pragma unroll
        for (int j=0;j<2;++j) acc[i][j] = (f32x4){0.f,0.f,0.f,0.f};
    const int c0r = tid >> 2;
    const int c0s = tid & 3;
    for (int k0 = 0; k0 < K; k0 += BK){
        uint4 av = *(const uint4*)&A [(bm + c0r)*K + k0 + c0s*8];
        uint4 bv = *(const uint4*)&Bt[(bn + c0r)*K + k0 + c0s*8];
        __syncthreads();
        *(uint4*)&As[c0r*ASTR + c0s*8] = av;
        *(uint4*)&Bs[c0r*ASTR + c0s*8] = bv;
        __syncthreads();
        short8 af[2], bfv[2];
        #pragma unroll
        for (int f=0; f<2; ++f){
            af[f]  = *(const short8*)&As[(wr + f*16 + ml)*ASTR + quad*8];
            bfv[f] = *(const short8*)&Bs[(wc + f*16 + ml)*ASTR + quad*8];
        }
        #pragma unroll
        for (int i=0;i<2;++i)
            #pragma unroll
            for (int j=0;j<2;++j)
                acc[i][j] = __builtin_amdgcn_mfma_f32_16x16x32_bf16(af[i], bfv[j], acc[i][j], 0,0,0);
    }
    #pragma unroll
    for (int i=0;i<2;++i){
        #pragma unroll
        for (int j=0;j<2;++j){
            const int gcol = bn + wc + j*16 + ml;
            const float bsv = bias[gcol];
            #pragma unroll
            for (int r=0;r<4;++r){
                const int grow = bm + wr + i*16 + quad*4 + r;
                float val = acc[i][j][r] + bsv;
                if (ACT == 2){
                    float v1 = __shfl_down(val, 1);
                    float v2 = __shfl_down(val, 2);
                    float v3 = __shfl_down(val, 3);
                    if ((l & 3) == 0){
                        int hd = gcol >> 2;
                        XCo[grow*HD + hd] = make_float2(val, v1);
                        float m2 = v2*v2 + v3*v3;
                        float s = sqrtf(m2)/(1.f + m2);
                        Ao[grow*HD + hd] = make_float2(v2*s, v3*s);
                    }
                } else if (ACT == 1){
                    val *= 1.f/(1.f + expf(-val));
                    Cb[grow*N + gcol] = f2bf(val);
                } else {
                    Cf[grow*N + gcol] = val;
                }
            }
        }
    }
}

// ---------- fused uext + parallel scan; writes Sb (bf16, hr-layout) + S255 fp32 ----------
__global__ __launch_bounds__(512) void upscan_kernel(const float2* __restrict__ Vinv,
        const float* __restrict__ hidr, const float* __restrict__ him,
        const float2* __restrict__ XC, const float2* __restrict__ Aseq,
        ushort* __restrict__ Sb, float2* __restrict__ S255){
    __shared__ float4 buf[2][2][LSEQ];
    __shared__ float2 vrow[2][64];
    __shared__ float2 inu[2];
    const int b = blockIdx.x;
    const int tid = threadIdx.x;
    const int g = tid >> 8, m = tid & 255;
    const int hn = b*2 + g;
    const int h = hn >> 6;
    if (m < 64) vrow[g][m] = Vinv[hn*64 + m];
    __syncthreads();
    float2 acc = make_float2(0.f, 0.f);
    const float2* xrow = &XC[m*HD + h*64];
    #pragma unroll 8
    for (int o=0;o<64;++o){
        float2 p = cmul(vrow[g][o], xrow[o]);
        acc.x += p.x; acc.y += p.y;
    }
    if (m == 0){
        float2 i0 = make_float2(0.f, 0.f);
        #pragma unroll 8
        for (int o=0;o<64;++o){
            float2 hv = make_float2(hidr[h*64+o], him[h*64+o]);
            float2 p = cmul(vrow[g][o], hv);
            i0.x += p.x; i0.y += p.y;
        }
        inu[g] = i0;
    }
    float2 a = Aseq[m*HD + hn];
    buf[0][g][m] = make_float4(a.x, a.y, acc.x, acc.y);
    __syncthreads();
    int pb = 0;
    #pragma unroll
    for (int d = 1; d < LSEQ; d <<= 1){
        float4 cur = buf[pb][g][m];
        float4 o2 = cur;
        if (m >= d){
            float4 prev = buf[pb][g][m-d];
            float2 cA = make_float2(cur.x, cur.y), cU = make_float2(cur.z, cur.w);
            float2 pA = make_float2(prev.x, prev.y), pU = make_float2(prev.z, prev.w);
            float2 nA = cmul(cA, pA);
            float2 nU = cmul(cA, pU);
            nU.x += cU.x; nU.y += cU.y;
            o2 = make_float4(nA.x, nA.y, nU.x, nU.y);
        }
        buf[pb^1][g][m] = o2;
        pb ^= 1;
        __syncthreads();
    }
    float4 t = buf[pb][g][m];
    float2 init = inu[g];
    float2 st = cmul(make_float2(t.x, t.y), init);
    st.x += t.z; st.y += t.w;
    Sb[m*DIMN + hn*2]   = f2bf(st.x);
    Sb[m*DIMN + hn*2+1] = f2bf(st.y);
    if (m == LSEQ-1) S255[hn] = st;
}

// ---------- old full vmul (fallback path only) ----------
__global__ __launch_bounds__(256) void vmul_kernel(const float* __restrict__ Vr,
                            const float* __restrict__ Vi,
                            const float2* __restrict__ S, ushort* __restrict__ hrb,
                            float* __restrict__ out_tail, int tail_n){
    int g = blockIdx.x*256 + threadIdx.x;
    int m = g >> 9, hn = g & 511;
    int h = hn >> 6;
    const float* vr = &Vr[hn*64];
    const float* vi = &Vi[hn*64];
    const float2* srow = &S[m*HD + h*64];
    float2 acc = make_float2(0.f, 0.f);
    #pragma unroll 8
    for (int o=0;o<64;++o){
        float2 v = make_float2(vr[o], vi[o]);
        float2 p = cmul(v, srow[o]);
        acc.x += p.x; acc.y += p.y;
    }
    hrb[m*DIMN + hn*2]   = f2bf(acc.x);
    hrb[m*DIMN + hn*2+1] = f2bf(acc.y);
    if (m == LSEQ-1){
        if (tail_n >= 1024){
            out_tail[hn]       = acc.x;
            out_tail[512 + hn] = acc.y;
        } else if (tail_n >= 512){
            out_tail[hn] = acc.x;
        }
    }
}

// fallback upscan writing fp32 S (old semantics)
__global__ __launch_bounds__(512) void upscan_f32_kernel(const float2* __restrict__ Vinv,
        const float* __restrict__ hidr, const float* __restrict__ him,
        const float2* __restrict__ XC, const float2* __restrict__ Aseq,
        float2* __restrict__ S){
    __shared__ float4 buf[2][2][LSEQ];
    __shared__ float2 vrow[2][64];
    __shared__ float2 inu[2];
    const int b = blockIdx.x;
    const int tid = threadIdx.x;
    const int g = tid >> 8, m = tid & 255;
    const int hn = b*2 + g;
    const int h = hn >> 6;
    if (m < 64) vrow[g][m] = Vinv[hn*64 + m];
    __syncthreads();
    float2 acc = make_float2(0.f, 0.f);
    const float2* xrow = &XC[m*HD + h*64];
    #pragma unroll 8
    for (int o=0;o<64;++o){
        float2 p = cmul(vrow[g][o], xrow[o]);
        acc.x += p.x; acc.y += p.y;
    }
    if (m == 0){
        float2 i0 = make_float2(0.f, 0.f);
        #pragma unroll 8
        for (int o=0;o<64;++o){
            float2 hv = make_float2(hidr[h*64+o], him[h*64+o]);
            float2 p = cmul(vrow[g][o], hv);
            i0.x += p.x; i0.y += p.y;
        }
        inu[g] = i0;
    }
    float2 a = Aseq[m*HD + hn];
    buf[0][g][m] = make_float4(a.x, a.y, acc.x, acc.y);
    __syncthreads();
    int pb = 0;
    #pragma unroll
    for (int d = 1; d < LSEQ; d <<= 1){
        float4 cur = buf[pb][g][m];
        float4 o2 = cur;
        if (m >= d){
            float4 prev = buf[pb][g][m-d];
            float2 cA = make_float2(cur.x, cur.y), cU = make_float2(cur.z, cur.w);
            float2 pA = make_float2(prev.x, prev.y), pU = make_float2(prev.z, prev.w);
            float2 nA = cmul(cA, pA);
            float2 nU = cmul(cA, pU);
            nU.x += cU.x; nU.y += cU.y;
            o2 = make_float4(nA.x, nA.y, nU.x, nU.y);
        }
        buf[pb^1][g][m] = o2;
        pb ^= 1;
        __syncthreads();
    }
    float4 t = buf[pb][g][m];
    float2 init = inu[g];
    float2 st = cmul(make_float2(t.x, t.y), init);
    st.x += t.z; st.y += t.w;
    S[m*HD + hn] = st;
}

extern "C" void kernel_launch(void* const* d_in, const int* in_sizes, int n_in,
                              void* d_out, int out_size, void* d_ws, size_t ws_size,
                              hipStream_t stream) {
    const float* x      = (const float*)d_in[0];
    const float* hidr   = (const float*)d_in[1];
    const float* hidi   = (const float*)d_in[2];
    const float* w_in1  = (const float*)d_in[3];
    const float* b_in1  = (const float*)d_in[4];
    const float* w_in2  = (const float*)d_in[5];
    const float* b_in2  = (const float*)d_in[6];
    const float* w_out1 = (const float*)d_in[7];
    const float* b_out1 = (const float*)d_in[8];
    const float* w_out2 = (const float*)d_in[9];
    const float* b_out2 = (const float*)d_in[10];
    const float* Vr     = (const float*)d_in[11];
    const float* Vi     = (const float*)d_in[12];
    float* out = (float*)d_out;
    const int tail_n = out_size - LSEQ*DIMN;
    char* ws = (char*)d_ws;

    if (ws_size >= 14946304u){
        float2* Vinv  = (float2*)(ws + 0);          // 256 KB
        ushort* w1t   = (ushort*)(ws + 262144);     // 2 MB
        ushort* w2t   = (ushort*)(ws + 2359296);    // 4 MB
        ushort* W3bt  = (ushort*)(ws + 6553600);    // 2 MB (was w3t)
        ushort* w4t   = (ushort*)(ws + 8650752);    // 2 MB
        ushort* x_bf  = (ushort*)(ws + 10747904);   // 512 KB (reused as y1_bf)
        ushort* t1_bf = (ushort*)(ws + 11272192);   // 512 KB (reused as Sb)
        float2* XC    = (float2*)(ws + 11796480);   // 1 MB
        float2* Aseq  = (float2*)(ws + 12845056);   // 1 MB
        float2* S255  = (float2*)(ws + 13893632);   // 4 KB
        ushort* y1_bf = x_bf;
        ushort* Sb    = t1_bf;

        prep_kernel<<<3208, 512, 0, stream>>>(x, w_in1, w_in2, w_out1, w_out2,
                                              Vr, Vi, x_bf, w1t, w2t, W3bt, w4t, Vinv);
        gemm_bt<1><<<dim3(16,4), 256, 0, stream>>>(x_bf, w1t, b_in1, nullptr, t1_bf,
                nullptr, nullptr, LSEQ, DIMN, DIMN, nullptr, nullptr, nullptr, nullptr, 0);
        gemm_bt<2><<<dim3(32,4), 256, 0, stream>>>(t1_bf, w2t, b_in2, nullptr, nullptr,
                XC, Aseq, LSEQ, 2048, DIMN, nullptr, nullptr, nullptr, nullptr, 0);
        upscan_kernel<<<256, 512, 0, stream>>>(Vinv, hidr, hidi, XC, Aseq, Sb, S255);
        gemm_bt<1><<<dim3(16,4), 256, 0, stream>>>(Sb, W3bt, b_out1, nullptr, y1_bf,
                nullptr, nullptr, LSEQ, DIMN, DIMN, nullptr, nullptr, nullptr, nullptr, 0);
        gemm_bt<0><<<dim3(16,4), 256, 0, stream>>>(y1_bf, w4t, b_out2, out, nullptr,
                nullptr, nullptr, LSEQ, DIMN, DIMN, Vr, Vi, S255, out + LSEQ*DIMN, tail_n);
    } else {
        // ---- R14 fallback: serial prep + full vmul path ----
        float2* Vinv  = (float2*)(ws + 0);
        ushort* wt    = (ushort*)(ws + 262144);
        ushort* x_bf  = (ushort*)(ws + 4456448);
        ushort* t1_bf = (ushort*)(ws + 4980736);
        float2* XC    = (float2*)(ws + 5505024);
        float2* Aseq  = (float2*)(ws + 6553600);
        float2* S     = (float2*)(ws + 7602176);
        ushort* y1_bf = x_bf;
        ushort* hr_bf = t1_bf;

        inv_kernel<<<NH, 512, 0, stream>>>(Vr, Vi, Vinv);
        cvt_bf16_kernel<<<LSEQ*DIMN/4/256, 256, 0, stream>>>(x, x_bf, LSEQ*DIMN/4);
        transpose_cvt<<<dim3(32,32), 256, 0, stream>>>(w_in1, wt, DIMN, DIMN);
        gemm_bt<1><<<dim3(16,4), 256, 0, stream>>>(x_bf, wt, b_in1, nullptr, t1_bf,
                nullptr, nullptr, LSEQ, DIMN, DIMN, nullptr, nullptr, nullptr, nullptr, 0);
        transpose_cvt<<<dim3(64,32), 256, 0, stream>>>(w_in2, wt, DIMN, 2048);
        gemm_bt<2><<<dim3(32,4), 256, 0, stream>>>(t1_bf, wt, b_in2, nullptr, nullptr,
                XC, Aseq, LSEQ, 2048, DIMN, nullptr, nullptr, nullptr, nullptr, 0);
        upscan_f32_kernel<<<256, 512, 0, stream>>>(Vinv, hidr, hidi, XC, Aseq, S);
        vmul_kernel<<<LSEQ*HD/256, 256, 0, stream>>>(Vr, Vi, S, hr_bf, out + LSEQ*DIMN, tail_n);
        transpose_cvt<<<dim3(32,32), 256, 0, stream>>>(w_out1, wt, DIMN, DIMN);
        gemm_bt<1><<<dim3(16,4), 256, 0, stream>>>(hr_bf, wt, b_out1, nullptr, y1_bf,
                nullptr, nullptr, LSEQ, DIMN, DIMN, nullptr, nullptr, nullptr, nullptr, 0);
        transpose_cvt<<<dim3(32,32), 256, 0, stream>>>(w_out2, wt, DIMN, DIMN);
        gemm_bt<0><<<dim3(16,4), 256, 0, stream>>>(y1_bf, wt, b_out2, out, nullptr,
                nullptr, nullptr, LSEQ, DIMN, DIMN, nullptr, nullptr, nullptr, nullptr, 0);
    }
}

// Round 18
// 198.024 us; speedup vs baseline: 1.1734x; 1.0741x over previous
//
#include <hip/hip_runtime.h>
#include <math.h>

#define DIMN 1024
#define NH 8
#define ND 64
#define LSEQ 256
#define HD 512      // NH*ND

typedef __attribute__((ext_vector_type(8))) short short8;
typedef __attribute__((ext_vector_type(4))) float f32x4;

__device__ __forceinline__ float2 cmul(float2 a, float2 b){
    return make_float2(a.x*b.x - a.y*b.y, a.x*b.y + a.y*b.x);
}
__device__ __forceinline__ ushort f2bf(float f){
    union { float f; unsigned u; } v; v.f = f;
    unsigned r = v.u + 0x7FFF + ((v.u >> 16) & 1);   // RNE
    return (ushort)(r >> 16);
}

#define ISTR 65
#define ASTR 40
#define BK 32

// ---------- blocked (NB=8) in-place Gauss-Jordan (R11/R14-verified) ----------
__device__ __forceinline__ void inv_gj_blocked(const float* __restrict__ Vr,
        const float* __restrict__ Vi, float2* __restrict__ Vinv,
        int h, int tid, float2* Mx){
    for (int idx = tid; idx < 4096; idx += 512){
        int i = idx >> 6, j = idx & 63;
        Mx[i*ISTR + j] = make_float2(Vr[h*4096 + idx], Vi[h*4096 + idx]);
    }
    __syncthreads();
    const int w = tid >> 6, l = tid & 63;
    const int rbase = w*8;
    for (int kb = 0; kb < 8; ++kb){
        const int k0 = kb*8;
        if (w == 0){
            float2 pr[8];
            #pragma unroll
            for (int m = 0; m < 8; ++m) pr[m] = Mx[l*ISTR + k0 + m];
            #pragma unroll
            for (int k = 0; k < 8; ++k){
                const int gk = k0 + k;
                float2 d; d.x = __shfl(pr[k].x, gk); d.y = __shfl(pr[k].y, gk);
                float im = 1.f/(d.x*d.x + d.y*d.y);
                float2 p = make_float2(d.x*im, -d.y*im);
                float2 spr[8];
                #pragma unroll
                for (int m = 0; m < 8; ++m){
                    float2 t; t.x = __shfl(pr[m].x, gk); t.y = __shfl(pr[m].y, gk);
                    spr[m] = (m == k) ? p : cmul(t, p);
                }
                float2 f = pr[k];
                if (l == gk){
                    #pragma unroll
                    for (int m = 0; m < 8; ++m) pr[m] = spr[m];
                } else {
                    #pragma unroll
                    for (int m = 0; m < 8; ++m){
                        float2 u = cmul(f, spr[m]);
                        if (m == k){ pr[m].x = -u.x;  pr[m].y = -u.y;  }
                        else       { pr[m].x -= u.x;  pr[m].y -= u.y;  }
                    }
                }
            }
            #pragma unroll
            for (int m = 0; m < 8; ++m) Mx[l*ISTR + k0 + m] = pr[m];
        }
        __syncthreads();
        float2 br[8];
        #pragma unroll
        for (int m = 0; m < 8; ++m) br[m] = Mx[(k0+m)*ISTR + l];
        __syncthreads();
        if (((unsigned)(l - k0)) >= 8u){
            #pragma unroll
            for (int rr = 0; rr < 8; ++rr){
                const int r = rbase + rr;
                float2 acc;
                if (((unsigned)(r - k0)) < 8u){ acc.x = 0.f; acc.y = 0.f; }
                else acc = Mx[r*ISTR + l];
                #pragma unroll
                for (int m = 0; m < 8; ++m){
                    float2 Pv = Mx[r*ISTR + k0 + m];
                    acc.x += Pv.x*br[m].x - Pv.y*br[m].y;
                    acc.y += Pv.x*br[m].y + Pv.y*br[m].x;
                }
                Mx[r*ISTR + l] = acc;
            }
        }
        __syncthreads();
    }
    for (int idx = tid; idx < 4096; idx += 512){
        int i = idx >> 6, j = idx & 63;
        Vinv[h*4096 + idx] = Mx[i*ISTR + j];
    }
}

// ---------- W3eff tile (R16-verified): fold V into w_out1 ----------
__device__ __forceinline__ void w3eff_tile(const float* __restrict__ Vr,
        const float* __restrict__ Vi, const float* __restrict__ w3,
        ushort* __restrict__ W3bt, int t, int tid, float* lds){
    const int n0 = (t & 31)*32;
    const int c0 = (t >> 5)*32;
    const int h  = c0 >> 7;
    const int og0 = (c0 & 127) >> 1;
    float* Vbr = lds;            // 64 x 16
    float* Vbi = lds + 1024;     // 64 x 16
    float* Wb  = lds + 2048;     // 128 x 32
    for (int q = tid; q < 1024; q += 512){
        int dd = q >> 4, oo = q & 15;
        Vbr[q] = Vr[(h*64+dd)*64 + og0 + oo];
        Vbi[q] = Vi[(h*64+dd)*64 + og0 + oo];
    }
    for (int q = tid; q < 4096; q += 512){
        int row = q >> 5, nn = q & 31;
        Wb[q] = w3[(h*128 + row)*1024 + n0 + nn];
    }
    __syncthreads();
    const int nn = tid & 31, oo = tid >> 5;    // oo 0..15
    float ar = 0.f, ai = 0.f;
    #pragma unroll 8
    for (int dd = 0; dd < 64; ++dd){
        float vr = Vbr[dd*16 + oo], vi = Vbi[dd*16 + oo];
        float w0 = Wb[(dd*2)*32 + nn], w1v = Wb[(dd*2+1)*32 + nn];
        ar += vr*w0 + vi*w1v;
        ai += -vi*w0 + vr*w1v;
    }
    W3bt[(n0+nn)*1024 + c0 + oo*2 + 0] = f2bf(ar);
    W3bt[(n0+nn)*1024 + c0 + oo*2 + 1] = f2bf(ai);
}

// ---------- gemm1 direct tile: one 64x64 tile by a 256-thread half-block.
// A = x (fp32, converted in-register); B = w1 (fp32 K x N, coalesced row reads
// + in-LDS transpose). Epilogue: silu -> bf16 t1. Both halves of a 512-thread
// block run identical loop/barrier counts -> __syncthreads safe.
__device__ __forceinline__ void gemm1_direct_tile(const float* __restrict__ x,
        const float* __restrict__ w1, const float* __restrict__ bias,
        ushort* __restrict__ Cb, int tile, int tid8, ushort* lds){
    ushort* As = lds;                  // 64*ASTR
    ushort* Bs = lds + 64*ASTR;        // 64*ASTR
    const int bm = (tile & 3)*64, bn = (tile >> 2)*64;
    const int wave = tid8 >> 6, l = tid8 & 63;
    const int wr = (wave >> 1)*32, wc = (wave & 1)*32;
    const int ml = l & 15, quad = l >> 4;
    f32x4 acc[2][2];
    #pragma unroll
    for (int i=0;i<2;++i)
        #pragma unroll
        for (int j=0;j<2;++j) acc[i][j] = (f32x4){0.f,0.f,0.f,0.f};
    const int c0r = tid8 >> 2, c0s = tid8 & 3;
    const int bn_n = tid8 & 63, bk0 = (tid8 >> 6)*8;
    for (int k0 = 0; k0 < DIMN; k0 += BK){
        float4 a0 = *(const float4*)&x[(bm+c0r)*DIMN + k0 + c0s*8];
        float4 a1 = *(const float4*)&x[(bm+c0r)*DIMN + k0 + c0s*8 + 4];
        float bv[8];
        #pragma unroll
        for (int kk = 0; kk < 8; ++kk)
            bv[kk] = w1[(k0 + bk0 + kk)*DIMN + bn + bn_n];
        __syncthreads();
        ushort4 u0; u0.x=f2bf(a0.x); u0.y=f2bf(a0.y); u0.z=f2bf(a0.z); u0.w=f2bf(a0.w);
        ushort4 u1; u1.x=f2bf(a1.x); u1.y=f2bf(a1.y); u1.z=f2bf(a1.z); u1.w=f2bf(a1.w);
        *(ushort4*)&As[c0r*ASTR + c0s*8]     = u0;
        *(ushort4*)&As[c0r*ASTR + c0s*8 + 4] = u1;
        #pragma unroll
        for (int kk = 0; kk < 8; ++kk)
            Bs[bn_n*ASTR + bk0 + kk] = f2bf(bv[kk]);
        __syncthreads();
        short8 af[2], bfv[2];
        #pragma unroll
        for (int f=0; f<2; ++f){
            af[f]  = *(const short8*)&As[(wr + f*16 + ml)*ASTR + quad*8];
            bfv[f] = *(const short8*)&Bs[(wc + f*16 + ml)*ASTR + quad*8];
        }
        #pragma unroll
        for (int i=0;i<2;++i)
            #pragma unroll
            for (int j=0;j<2;++j)
                acc[i][j] = __builtin_amdgcn_mfma_f32_16x16x32_bf16(af[i], bfv[j], acc[i][j], 0,0,0);
    }
    #pragma unroll
    for (int i=0;i<2;++i){
        #pragma unroll
        for (int j=0;j<2;++j){
            const int gcol = bn + wc + j*16 + ml;
            const float bsv = bias[gcol];
            #pragma unroll
            for (int r=0;r<4;++r){
                const int grow = bm + wr + i*16 + quad*4 + r;
                float val = acc[i][j][r] + bsv;
                val *= 1.f/(1.f + expf(-val));
                Cb[grow*DIMN + gcol] = f2bf(val);
            }
        }
    }
}

// ---------- mix1: gemm1(direct) + inv + transposes(w2,w4) + W3eff, one dispatch ----------
// blocks 0-31: gemm1 (2 tiles each, 64 tiles); 32-39: inv;
// 40-1063: w2 transpose (1024 units = 2048 tiles); 1064-1575: w4 (512 units);
// 1576-2599: W3eff (1024 units). R17 bug: w2/w4 unit counts were halved.
__global__ __launch_bounds__(512) void mix1_kernel(
        const float* __restrict__ x,
        const float* __restrict__ w1, const float* __restrict__ w2,
        const float* __restrict__ w3, const float* __restrict__ w4,
        const float* __restrict__ Vr, const float* __restrict__ Vi,
        const float* __restrict__ b1,
        ushort* __restrict__ t1_bf,
        ushort* __restrict__ w2t, ushort* __restrict__ W3bt,
        ushort* __restrict__ w4t, float2* __restrict__ Vinv){
    __shared__ __align__(16) char lds_raw[33280];
    const int b = blockIdx.x;
    const int tid = threadIdx.x;
    const int half = tid >> 8;

    if (b < 32){
        gemm1_direct_tile(x, w1, b1, t1_bf, b*2 + half, tid & 255,
                          (ushort*)lds_raw + half*(128*ASTR));
        return;
    }
    if (b < 40){
        inv_gj_blocked(Vr, Vi, Vinv, b - 32, tid, (float2*)lds_raw);
        return;
    }
    int widx = b - 40;
    if (widx >= 1536){
        w3eff_tile(Vr, Vi, w3, W3bt, widx - 1536, tid, (float*)lds_raw);
        return;
    }
    const float* W; ushort* Wt; int K = 1024, N;
    if (widx < 1024){ W = w2; Wt = w2t; N = 2048; }
    else            { W = w4; Wt = w4t; N = 1024; widx -= 1024; }
    const int t = widx*2 + half;
    const int tiles_n = N >> 5;
    const int n0 = (t % tiles_n) * 32, k0 = (t / tiles_n) * 32;
    float* tile = (float*)lds_raw + half*(32*33);
    const int tx = tid & 31, ty = (tid >> 5) & 7;
    #pragma unroll
    for (int i = 0; i < 4; ++i)
        tile[(ty + i*8)*33 + tx] = W[(k0 + ty + i*8)*N + n0 + tx];
    __syncthreads();
    #pragma unroll
    for (int i = 0; i < 4; ++i){
        int r = ty + i*8;
        Wt[(n0 + r)*K + k0 + tx] = f2bf(tile[tx*33 + r]);
    }
}

// ---------- serial-fallback kernels (R14 path; used only if ws too small) ----------
__global__ __launch_bounds__(512) void inv_kernel(const float* __restrict__ Vr,
                                                  const float* __restrict__ Vi,
                                                  float2* __restrict__ Vinv){
    __shared__ float2 Mx[64*ISTR];
    inv_gj_blocked(Vr, Vi, Vinv, blockIdx.x, threadIdx.x, Mx);
}

__global__ __launch_bounds__(256) void transpose_cvt(const float* __restrict__ W,
                 ushort* __restrict__ Wt, int K, int N){
    __shared__ float tile[32][33];
    const int n0 = blockIdx.x * 32, k0 = blockIdx.y * 32;
    const int tx = threadIdx.x & 31, ty = threadIdx.x >> 5;
    #pragma unroll
    for (int i = 0; i < 4; ++i)
        tile[ty + i*8][tx] = W[(k0 + ty + i*8)*N + n0 + tx];
    __syncthreads();
    #pragma unroll
    for (int i = 0; i < 4; ++i){
        int r = ty + i*8;
        Wt[(n0 + r)*K + k0 + tx] = f2bf(tile[tx][r]);
    }
}

__global__ __launch_bounds__(256) void cvt_bf16_kernel(const float* __restrict__ in,
                                 ushort* __restrict__ o, int n4){
    int i = blockIdx.x*256 + threadIdx.x;
    if (i < n4){
        float4 v = ((const float4*)in)[i];
        ushort4 u; u.x=f2bf(v.x); u.y=f2bf(v.y); u.z=f2bf(v.z); u.w=f2bf(v.w);
        ((ushort4*)o)[i] = u;
    }
}

// ---------- bf16 MFMA GEMM, 64x64 tile (R14-verified). ACT0 block(0,0) also
// computes the fp32 hidden_next tail from S255. ----------
#define BM 64
#define BN 64
template<int ACT>
__global__ __launch_bounds__(256) void gemm_bt(const ushort* __restrict__ A,
                 const ushort* __restrict__ Bt, const float* __restrict__ bias,
                 float* __restrict__ Cf, ushort* __restrict__ Cb,
                 float2* __restrict__ XCo, float2* __restrict__ Ao,
                 int M, int N, int K,
                 const float* __restrict__ tVr, const float* __restrict__ tVi,
                 const float2* __restrict__ S255, float* __restrict__ out_tail,
                 int tail_n){
    __shared__ ushort As[BM*ASTR];
    __shared__ ushort Bs[BN*ASTR];
    const int tid = threadIdx.x;
    const int bm = blockIdx.y * BM, bn = blockIdx.x * BN;
    const int wave = tid >> 6, l = tid & 63;
    const int wr = (wave >> 1) * 32, wc = (wave & 1) * 32;
    const int ml = l & 15, quad = l >> 4;

    if (ACT == 0 && out_tail != nullptr && blockIdx.x == 0 && blockIdx.y == 0){
        for (int hn = tid; hn < 512; hn += 256){
            int h = hn >> 6;
            float2 acc2 = make_float2(0.f, 0.f);
            #pragma unroll 8
            for (int o = 0; o < 64; ++o){
                float2 v = make_float2(tVr[hn*64+o], tVi[hn*64+o]);
                float2 p = cmul(v, S255[h*64+o]);
                acc2.x += p.x; acc2.y += p.y;
            }
            if (tail_n >= 1024){
                out_tail[hn]       = acc2.x;
                out_tail[512 + hn] = acc2.y;
            } else if (tail_n >= 512){
                out_tail[hn] = acc2.x;
            }
        }
    }

    f32x4 acc[2][2];
    #pragma unroll
    for (int i=0;i<2;++i)
        #pragma unroll
        for (int j=0;j<2;++j) acc[i][j] = (f32x4){0.f,0.f,0.f,0.f};
    const int c0r = tid >> 2;
    const int c0s = tid & 3;
    for (int k0 = 0; k0 < K; k0 += BK){
        uint4 av = *(const uint4*)&A [(bm + c0r)*K + k0 + c0s*8];
        uint4 bv = *(const uint4*)&Bt[(bn + c0r)*K + k0 + c0s*8];
        __syncthreads();
        *(uint4*)&As[c0r*ASTR + c0s*8] = av;
        *(uint4*)&Bs[c0r*ASTR + c0s*8] = bv;
        __syncthreads();
        short8 af[2], bfv[2];
        #pragma unroll
        for (int f=0; f<2; ++f){
            af[f]  = *(const short8*)&As[(wr + f*16 + ml)*ASTR + quad*8];
            bfv[f] = *(const short8*)&Bs[(wc + f*16 + ml)*ASTR + quad*8];
        }
        #pragma unroll
        for (int i=0;i<2;++i)
            #pragma unroll
            for (int j=0;j<2;++j)
                acc[i][j] = __builtin_amdgcn_mfma_f32_16x16x32_bf16(af[i], bfv[j], acc[i][j], 0,0,0);
    }
    #pragma unroll
    for (int i=0;i<2;++i){
        #pragma unroll
        for (int j=0;j<2;++j){
            const int gcol = bn + wc + j*16 + ml;
            const float bsv = bias[gcol];
            #pragma unroll
            for (int r=0;r<4;++r){
                const int grow = bm + wr + i*16 + quad*4 + r;
                float val = acc[i][j][r] + bsv;
                if (ACT == 2){
                    float v1 = __shfl_down(val, 1);
                    float v2 = __shfl_down(val, 2);
                    float v3 = __shfl_down(val, 3);
                    if ((l & 3) == 0){
                        int hd = gcol >> 2;
                        XCo[grow*HD + hd] = make_float2(val, v1);
                        float m2 = v2*v2 + v3*v3;
                        float s = sqrtf(m2)/(1.f + m2);
                        Ao[grow*HD + hd] = make_float2(v2*s, v3*s);
                    }
                } else if (ACT == 1){
                    val *= 1.f/(1.f + expf(-val));
                    Cb[grow*N + gcol] = f2bf(val);
                } else {
                    Cf[grow*N + gcol] = val;
                }
            }
        }
    }
}

// ---------- fused uext + parallel scan; writes Sb (bf16, hr-layout) + S255 fp32 ----------
__global__ __launch_bounds__(512) void upscan_kernel(const float2* __restrict__ Vinv,
        const float* __restrict__ hidr, const float* __restrict__ him,
        const float2* __restrict__ XC, const float2* __restrict__ Aseq,
        ushort* __restrict__ Sb, float2* __restrict__ S255){
    __shared__ float4 buf[2][2][LSEQ];
    __shared__ float2 vrow[2][64];
    __shared__ float2 inu[2];
    const int b = blockIdx.x;
    const int tid = threadIdx.x;
    const int g = tid >> 8, m = tid & 255;
    const int hn = b*2 + g;
    const int h = hn >> 6;
    if (m < 64) vrow[g][m] = Vinv[hn*64 + m];
    __syncthreads();
    float2 acc = make_float2(0.f, 0.f);
    const float2* xrow = &XC[m*HD + h*64];
    #pragma unroll 8
    for (int o=0;o<64;++o){
        float2 p = cmul(vrow[g][o], xrow[o]);
        acc.x += p.x; acc.y += p.y;
    }
    if (m == 0){
        float2 i0 = make_float2(0.f, 0.f);
        #pragma unroll 8
        for (int o=0;o<64;++o){
            float2 hv = make_float2(hidr[h*64+o], him[h*64+o]);
            float2 p = cmul(vrow[g][o], hv);
            i0.x += p.x; i0.y += p.y;
        }
        inu[g] = i0;
    }
    float2 a = Aseq[m*HD + hn];
    buf[0][g][m] = make_float4(a.x, a.y, acc.x, acc.y);
    __syncthreads();
    int pb = 0;
    #pragma unroll
    for (int d = 1; d < LSEQ; d <<= 1){
        float4 cur = buf[pb][g][m];
        float4 o2 = cur;
        if (m >= d){
            float4 prev = buf[pb][g][m-d];
            float2 cA = make_float2(cur.x, cur.y), cU = make_float2(cur.z, cur.w);
            float2 pA = make_float2(prev.x, prev.y), pU = make_float2(prev.z, prev.w);
            float2 nA = cmul(cA, pA);
            float2 nU = cmul(cA, pU);
            nU.x += cU.x; nU.y += cU.y;
            o2 = make_float4(nA.x, nA.y, nU.x, nU.y);
        }
        buf[pb^1][g][m] = o2;
        pb ^= 1;
        __syncthreads();
    }
    float4 t = buf[pb][g][m];
    float2 init = inu[g];
    float2 st = cmul(make_float2(t.x, t.y), init);
    st.x += t.z; st.y += t.w;
    Sb[m*DIMN + hn*2]   = f2bf(st.x);
    Sb[m*DIMN + hn*2+1] = f2bf(st.y);
    if (m == LSEQ-1) S255[hn] = st;
}

// ---------- fallback-only kernels ----------
__global__ __launch_bounds__(256) void vmul_kernel(const float* __restrict__ Vr,
                            const float* __restrict__ Vi,
                            const float2* __restrict__ S, ushort* __restrict__ hrb,
                            float* __restrict__ out_tail, int tail_n){
    int g = blockIdx.x*256 + threadIdx.x;
    int m = g >> 9, hn = g & 511;
    int h = hn >> 6;
    const float* vr = &Vr[hn*64];
    const float* vi = &Vi[hn*64];
    const float2* srow = &S[m*HD + h*64];
    float2 acc = make_float2(0.f, 0.f);
    #pragma unroll 8
    for (int o=0;o<64;++o){
        float2 v = make_float2(vr[o], vi[o]);
        float2 p = cmul(v, srow[o]);
        acc.x += p.x; acc.y += p.y;
    }
    hrb[m*DIMN + hn*2]   = f2bf(acc.x);
    hrb[m*DIMN + hn*2+1] = f2bf(acc.y);
    if (m == LSEQ-1){
        if (tail_n >= 1024){
            out_tail[hn]       = acc.x;
            out_tail[512 + hn] = acc.y;
        } else if (tail_n >= 512){
            out_tail[hn] = acc.x;
        }
    }
}

__global__ __launch_bounds__(512) void upscan_f32_kernel(const float2* __restrict__ Vinv,
        const float* __restrict__ hidr, const float* __restrict__ him,
        const float2* __restrict__ XC, const float2* __restrict__ Aseq,
        float2* __restrict__ S){
    __shared__ float4 buf[2][2][LSEQ];
    __shared__ float2 vrow[2][64];
    __shared__ float2 inu[2];
    const int b = blockIdx.x;
    const int tid = threadIdx.x;
    const int g = tid >> 8, m = tid & 255;
    const int hn = b*2 + g;
    const int h = hn >> 6;
    if (m < 64) vrow[g][m] = Vinv[hn*64 + m];
    __syncthreads();
    float2 acc = make_float2(0.f, 0.f);
    const float2* xrow = &XC[m*HD + h*64];
    #pragma unroll 8
    for (int o=0;o<64;++o){
        float2 p = cmul(vrow[g][o], xrow[o]);
        acc.x += p.x; acc.y += p.y;
    }
    if (m == 0){
        float2 i0 = make_float2(0.f, 0.f);
        #pragma unroll 8
        for (int o=0;o<64;++o){
            float2 hv = make_float2(hidr[h*64+o], him[h*64+o]);
            float2 p = cmul(vrow[g][o], hv);
            i0.x += p.x; i0.y += p.y;
        }
        inu[g] = i0;
    }
    float2 a = Aseq[m*HD + hn];
    buf[0][g][m] = make_float4(a.x, a.y, acc.x, acc.y);
    __syncthreads();
    int pb = 0;
    #pragma unroll
    for (int d = 1; d < LSEQ; d <<= 1){
        float4 cur = buf[pb][g][m];
        float4 o2 = cur;
        if (m >= d){
            float4 prev = buf[pb][g][m-d];
            float2 cA = make_float2(cur.x, cur.y), cU = make_float2(cur.z, cur.w);
            float2 pA = make_float2(prev.x, prev.y), pU = make_float2(prev.z, prev.w);
            float2 nA = cmul(cA, pA);
            float2 nU = cmul(cA, pU);
            nU.x += cU.x; nU.y += cU.y;
            o2 = make_float4(nA.x, nA.y, nU.x, nU.y);
        }
        buf[pb^1][g][m] = o2;
        pb ^= 1;
        __syncthreads();
    }
    float4 t = buf[pb][g][m];
    float2 init = inu[g];
    float2 st = cmul(make_float2(t.x, t.y), init);
    st.x += t.z; st.y += t.w;
    S[m*HD + hn] = st;
}

extern "C" void kernel_launch(void* const* d_in, const int* in_sizes, int n_in,
                              void* d_out, int out_size, void* d_ws, size_t ws_size,
                              hipStream_t stream) {
    const float* x      = (const float*)d_in[0];
    const float* hidr   = (const float*)d_in[1];
    const float* hidi   = (const float*)d_in[2];
    const float* w_in1  = (const float*)d_in[3];
    const float* b_in1  = (const float*)d_in[4];
    const float* w_in2  = (const float*)d_in[5];
    const float* b_in2  = (const float*)d_in[6];
    const float* w_out1 = (const float*)d_in[7];
    const float* b_out1 = (const float*)d_in[8];
    const float* w_out2 = (const float*)d_in[9];
    const float* b_out2 = (const float*)d_in[10];
    const float* Vr     = (const float*)d_in[11];
    const float* Vi     = (const float*)d_in[12];
    float* out = (float*)d_out;
    const int tail_n = out_size - LSEQ*DIMN;
    char* ws = (char*)d_ws;

    if (ws_size >= 14946304u){
        float2* Vinv  = (float2*)(ws + 0);          // 256 KB
        ushort* w2t   = (ushort*)(ws + 2359296);    // 4 MB
        ushort* W3bt  = (ushort*)(ws + 6553600);    // 2 MB
        ushort* w4t   = (ushort*)(ws + 8650752);    // 2 MB
        ushort* y1_bf = (ushort*)(ws + 10747904);   // 512 KB
        ushort* t1_bf = (ushort*)(ws + 11272192);   // 512 KB (reused as Sb)
        float2* XC    = (float2*)(ws + 11796480);   // 1 MB
        float2* Aseq  = (float2*)(ws + 12845056);   // 1 MB
        float2* S255  = (float2*)(ws + 13893632);   // 4 KB
        ushort* Sb    = t1_bf;

        mix1_kernel<<<2600, 512, 0, stream>>>(x, w_in1, w_in2, w_out1, w_out2,
                                              Vr, Vi, b_in1, t1_bf, w2t, W3bt, w4t, Vinv);
        gemm_bt<2><<<dim3(32,4), 256, 0, stream>>>(t1_bf, w2t, b_in2, nullptr, nullptr,
                XC, Aseq, LSEQ, 2048, DIMN, nullptr, nullptr, nullptr, nullptr, 0);
        upscan_kernel<<<256, 512, 0, stream>>>(Vinv, hidr, hidi, XC, Aseq, Sb, S255);
        gemm_bt<1><<<dim3(16,4), 256, 0, stream>>>(Sb, W3bt, b_out1, nullptr, y1_bf,
                nullptr, nullptr, LSEQ, DIMN, DIMN, nullptr, nullptr, nullptr, nullptr, 0);
        gemm_bt<0><<<dim3(16,4), 256, 0, stream>>>(y1_bf, w4t, b_out2, out, nullptr,
                nullptr, nullptr, LSEQ, DIMN, DIMN, Vr, Vi, S255, out + LSEQ*DIMN, tail_n);
    } else {
        // ---- R14 fallback: serial prep + full vmul path ----
        float2* Vinv  = (float2*)(ws + 0);
        ushort* wt    = (ushort*)(ws + 262144);
        ushort* x_bf  = (ushort*)(ws + 4456448);
        ushort* t1_bf = (ushort*)(ws + 4980736);
        float2* XC    = (float2*)(ws + 5505024);
        float2* Aseq  = (float2*)(ws + 6553600);
        float2* S     = (float2*)(ws + 7602176);
        ushort* y1_bf = x_bf;
        ushort* hr_bf = t1_bf;

        inv_kernel<<<NH, 512, 0, stream>>>(Vr, Vi, Vinv);
        cvt_bf16_kernel<<<LSEQ*DIMN/4/256, 256, 0, stream>>>(x, x_bf, LSEQ*DIMN/4);
        transpose_cvt<<<dim3(32,32), 256, 0, stream>>>(w_in1, wt, DIMN, DIMN);
        gemm_bt<1><<<dim3(16,4), 256, 0, stream>>>(x_bf, wt, b_in1, nullptr, t1_bf,
                nullptr, nullptr, LSEQ, DIMN, DIMN, nullptr, nullptr, nullptr, nullptr, 0);
        transpose_cvt<<<dim3(64,32), 256, 0, stream>>>(w_in2, wt, DIMN, 2048);
        gemm_bt<2><<<dim3(32,4), 256, 0, stream>>>(t1_bf, wt, b_in2, nullptr, nullptr,
                XC, Aseq, LSEQ, 2048, DIMN, nullptr, nullptr, nullptr, nullptr, 0);
        upscan_f32_kernel<<<256, 512, 0, stream>>>(Vinv, hidr, hidi, XC, Aseq, S);
        vmul_kernel<<<LSEQ*HD/256, 256, 0, stream>>>(Vr, Vi, S, hr_bf, out + LSEQ*DIMN, tail_n);
        transpose_cvt<<<dim3(32,32), 256, 0, stream>>>(w_out1, wt, DIMN, DIMN);
        gemm_bt<1><<<dim3(16,4), 256, 0, stream>>>(hr_bf, wt, b_out1, nullptr, y1_bf,
                nullptr, nullptr, LSEQ, DIMN, DIMN, nullptr, nullptr, nullptr, nullptr, 0);
        transpose_cvt<<<dim3(32,32), 256, 0, stream>>>(w_out2, wt, DIMN, DIMN);
        gemm_bt<0><<<dim3(16,4), 256, 0, stream>>>(y1_bf, wt, b_out2, out, nullptr,
                nullptr, nullptr, LSEQ, DIMN, DIMN, nullptr, nullptr, nullptr, nullptr, 0);
    }
}